// Round 1
// baseline (327.332 us; speedup 1.0000x reference)
//
#include <hip/hip_runtime.h>
#include <hip/hip_bf16.h>
#include <stdint.h>

// Problem constants
#define AN 64
#define HN 1024
#define BN 512
#define GAUSS_CONST (-3.989422804014327f)   // V0 / (sqrt(2*pi)*sigma0)
#define INV_2SIG2 2.0f

typedef __attribute__((ext_vector_type(8))) short short8;
typedef __attribute__((ext_vector_type(4))) float floatx4;

__device__ inline unsigned short f2bf(float f) {
  __hip_bfloat16 h = __float2bfloat16(f);        // RNE
  return *reinterpret_cast<unsigned short*>(&h);
}

__device__ inline void gload_lds16(const void* g, void* l) {
  __builtin_amdgcn_global_load_lds(
      (const __attribute__((address_space(1))) void*)g,
      (__attribute__((address_space(3))) void*)l, 16, 0, 0);
}

// ---------------------------------------------------------------------------
// prep: W2T bf16, W2 bf16, W1T f32, c_j = sum_a W1[a,j]^2
__global__ __launch_bounds__(256) void k_prep(
    const float* __restrict__ W1, const float* __restrict__ W2,
    unsigned short* __restrict__ W2T, unsigned short* __restrict__ W2bf,
    float* __restrict__ W1T, float* __restrict__ c) {
  int idx = blockIdx.x * 256 + threadIdx.x;   // exactly 1M threads
  float v = W2[idx];
  W2bf[idx] = f2bf(v);
  int j = idx >> 10, k = idx & 1023;
  W2T[k * HN + j] = f2bf(v);
  if (idx < AN * HN) {
    int a = idx >> 10, jj = idx & 1023;
    W1T[jj * AN + a] = W1[idx];
  }
  if (idx < HN) {
    float s = 0.f;
    for (int a = 0; a < AN; ++a) { float x = W1[a * HN + idx]; s += x * x; }
    c[idx] = s;
  }
}

// ---------------------------------------------------------------------------
// layer 1 forward + pot + gint.  1 block = 1 sample.
__global__ __launch_bounds__(256) void k_fwd1(
    const float* __restrict__ x, const float* __restrict__ W1,
    const float* __restrict__ b1, const float* __restrict__ c,
    unsigned short* __restrict__ h1bf, float* __restrict__ t1f,
    float* __restrict__ a1, float* __restrict__ potgint) {
  __shared__ float xs[AN];
  __shared__ float red[4];
  int s = blockIdx.x, tid = threadIdx.x;
  if (tid < AN) xs[tid] = x[s * AN + tid];
  __syncthreads();
  #pragma unroll
  for (int cc = 0; cc < 4; ++cc) {
    int j = tid + cc * 256;
    float z = b1[j];
    #pragma unroll 8
    for (int a = 0; a < AN; ++a) z += xs[a] * W1[a * HN + j];
    float h = tanhf(z), t = 1.f - h * h;
    h1bf[s * HN + j] = f2bf(h);
    t1f[s * HN + j] = t;
    a1[s * HN + j] = c[j] * h * t;
  }
  // pot + gint
  float val = 0.f;
  #pragma unroll
  for (int p = 0; p < 16; ++p) {
    int idx = tid + p * 256;
    int i = idx >> 6, jj = idx & 63;
    if (jj > i) { float d = xs[i] - xs[jj]; val += __expf(-INV_2SIG2 * d * d); }
  }
  val *= GAUSS_CONST;
  if (tid < AN) val += 0.5f * xs[tid] * xs[tid];
  #pragma unroll
  for (int o = 32; o > 0; o >>= 1) val += __shfl_down(val, o, 64);
  if ((tid & 63) == 0) red[tid >> 6] = val;
  __syncthreads();
  if (tid == 0) potgint[s] = red[0] + red[1] + red[2] + red[3];
}

// ---------------------------------------------------------------------------
// z2 = h1 @ W2 + b2 -> dcoef = -2 h2 t2 W3, v = t2*W3 (bf16)
// block tile 16 samples x 64 cols, split-K over 4 waves.
__global__ __launch_bounds__(256) void k_z2(
    const unsigned short* __restrict__ h1bf, const unsigned short* __restrict__ W2T,
    const float* __restrict__ b2, const float* __restrict__ W3,
    float* __restrict__ dcoef, unsigned short* __restrict__ vbf) {
  __shared__ float redL[4 * 16 * 64];
  int n0 = blockIdx.x * 64, m0 = blockIdx.y * 16;
  int tid = threadIdx.x, w = tid >> 6, l = tid & 63, lr = l & 15, kg = l >> 4;
  floatx4 acc[4];
  #pragma unroll
  for (int nf = 0; nf < 4; ++nf) acc[nf] = (floatx4){0.f, 0.f, 0.f, 0.f};
  int arow = m0 + lr;
  for (int kt = 0; kt < 8; ++kt) {
    int kb = w * 256 + kt * 32 + kg * 8;
    short8 af = *reinterpret_cast<const short8*>(&h1bf[arow * HN + kb]);
    #pragma unroll
    for (int nf = 0; nf < 4; ++nf) {
      short8 bf_ = *reinterpret_cast<const short8*>(&W2T[(n0 + nf * 16 + lr) * HN + kb]);
      acc[nf] = __builtin_amdgcn_mfma_f32_16x16x32_bf16(af, bf_, acc[nf], 0, 0, 0);
    }
  }
  #pragma unroll
  for (int nf = 0; nf < 4; ++nf)
    #pragma unroll
    for (int r = 0; r < 4; ++r)
      redL[w * 1024 + (kg * 4 + r) * 64 + nf * 16 + lr] = acc[nf][r];
  __syncthreads();
  #pragma unroll
  for (int t = 0; t < 4; ++t) {
    int e = tid + t * 256;
    float z = redL[e] + redL[1024 + e] + redL[2048 + e] + redL[3072 + e];
    int row = e >> 6, col = e & 63;
    int s = m0 + row, k2 = n0 + col;
    z += b2[k2];
    float h = tanhf(z), tt = 1.f - h * h, w3 = W3[k2];
    dcoef[s * HN + k2] = -2.f * h * tt * w3;
    vbf[s * HN + k2] = f2bf(tt * w3);
  }
}

// ---------------------------------------------------------------------------
// w = v @ W2^T  (w[s,j] = sum_k v[s,k] W2[j,k]) -> store f32
__global__ __launch_bounds__(256) void k_w(
    const unsigned short* __restrict__ vbf, const unsigned short* __restrict__ W2bf,
    float* __restrict__ wbuf) {
  __shared__ float redL[4 * 16 * 64];
  int n0 = blockIdx.x * 64, m0 = blockIdx.y * 16;
  int tid = threadIdx.x, w = tid >> 6, l = tid & 63, lr = l & 15, kg = l >> 4;
  floatx4 acc[4];
  #pragma unroll
  for (int nf = 0; nf < 4; ++nf) acc[nf] = (floatx4){0.f, 0.f, 0.f, 0.f};
  int arow = m0 + lr;
  for (int kt = 0; kt < 8; ++kt) {
    int kb = w * 256 + kt * 32 + kg * 8;
    short8 af = *reinterpret_cast<const short8*>(&vbf[arow * HN + kb]);
    #pragma unroll
    for (int nf = 0; nf < 4; ++nf) {
      short8 bf_ = *reinterpret_cast<const short8*>(&W2bf[(n0 + nf * 16 + lr) * HN + kb]);
      acc[nf] = __builtin_amdgcn_mfma_f32_16x16x32_bf16(af, bf_, acc[nf], 0, 0, 0);
    }
  }
  #pragma unroll
  for (int nf = 0; nf < 4; ++nf)
    #pragma unroll
    for (int r = 0; r < 4; ++r)
      redL[w * 1024 + (kg * 4 + r) * 64 + nf * 16 + lr] = acc[nf][r];
  __syncthreads();
  #pragma unroll
  for (int t = 0; t < 4; ++t) {
    int e = tid + t * 256;
    float z = redL[e] + redL[1024 + e] + redL[2048 + e] + redL[3072 + e];
    int row = e >> 6, col = e & 63;
    wbuf[(m0 + row) * HN + (n0 + col)] = z;
  }
}

// ---------------------------------------------------------------------------
// BIG: q[s,k] = sum_a M[a,k]^2,  M = (W1 .* t1[s]) @ W2   (K=1024 in-block)
// 128x128 tile (2 samples x 128 cols), BK=64, double-buffered.
__global__ __launch_bounds__(256) void k_big(
    const float* __restrict__ W1, const float* __restrict__ t1f,
    const unsigned short* __restrict__ W2T, float* __restrict__ q) {
  __shared__ unsigned short Ab[2][128 * 64];   // [row(2 samples x 64a)][j]
  __shared__ unsigned short Bb[2][128 * 64];   // [col][j]
  int n0 = blockIdx.x * 128;
  int s0 = blockIdx.y * 2;
  int tid = threadIdx.x, w = tid >> 6, l = tid & 63;
  int lr = l & 15, kg = l >> 4;
  int rh = w >> 1, ch = w & 1;                 // wave: 64-row half (sample), 64-col half

  // A staging geometry: thread covers row ar, 32 j's (4 chunks of 8)
  int ar = tid >> 1;
  int ajh = (tid & 1) * 32;
  int sA = s0 + (ar >> 6);
  int aa = ar & 63;

  auto stage = [&](int buf, int kt) {
    int j0 = kt * 64;
    // issue A-operand global loads first (f32 W1 + f32 t1)
    floatx4 wv[8], tv[8];
    #pragma unroll
    for (int cc = 0; cc < 4; ++cc) {
      int j = ajh + cc * 8;
      const floatx4* wp = reinterpret_cast<const floatx4*>(&W1[aa * HN + j0 + j]);
      const floatx4* tp = reinterpret_cast<const floatx4*>(&t1f[sA * HN + j0 + j]);
      wv[cc * 2] = wp[0]; wv[cc * 2 + 1] = wp[1];
      tv[cc * 2] = tp[0]; tv[cc * 2 + 1] = tp[1];
    }
    // B via async global->LDS (linear dest, 16B)
    #pragma unroll
    for (int p = 0; p < 4; ++p) {
      int n = p * 32 + (tid >> 3);
      int j = (tid & 7) * 8;
      gload_lds16(&W2T[(n0 + n) * HN + j0 + j], &Bb[buf][p * 2048 + tid * 8]);
    }
    // pack P = W1*t1 -> bf16, write to LDS
    #pragma unroll
    for (int cc = 0; cc < 4; ++cc) {
      int j = ajh + cc * 8;
      short8 out;
      #pragma unroll
      for (int e = 0; e < 4; ++e) out[e] = (short)f2bf(wv[cc * 2][e] * tv[cc * 2][e]);
      #pragma unroll
      for (int e = 0; e < 4; ++e) out[4 + e] = (short)f2bf(wv[cc * 2 + 1][e] * tv[cc * 2 + 1][e]);
      *reinterpret_cast<short8*>(&Ab[buf][ar * 64 + j]) = out;
    }
  };

  floatx4 acc[4][4];
  #pragma unroll
  for (int mf = 0; mf < 4; ++mf)
    #pragma unroll
    for (int nf = 0; nf < 4; ++nf) acc[mf][nf] = (floatx4){0.f, 0.f, 0.f, 0.f};

  stage(0, 0);
  __syncthreads();
  for (int kt = 0; kt < 16; ++kt) {
    int buf = kt & 1;
    if (kt < 15) stage(buf ^ 1, kt + 1);
    #pragma unroll
    for (int ks = 0; ks < 2; ++ks) {
      int kb = ks * 32 + kg * 8;
      short8 afr[4], bfr[4];
      #pragma unroll
      for (int mf = 0; mf < 4; ++mf)
        afr[mf] = *reinterpret_cast<const short8*>(&Ab[buf][(rh * 64 + mf * 16 + lr) * 64 + kb]);
      #pragma unroll
      for (int nf = 0; nf < 4; ++nf)
        bfr[nf] = *reinterpret_cast<const short8*>(&Bb[buf][(ch * 64 + nf * 16 + lr) * 64 + kb]);
      #pragma unroll
      for (int mf = 0; mf < 4; ++mf)
        #pragma unroll
        for (int nf = 0; nf < 4; ++nf)
          acc[mf][nf] = __builtin_amdgcn_mfma_f32_16x16x32_bf16(afr[mf], bfr[nf], acc[mf][nf], 0, 0, 0);
    }
    __syncthreads();
  }

  // epilogue: q[s, col] = sum over 64 rows of M^2
  int sOut = s0 + rh;
  #pragma unroll
  for (int nf = 0; nf < 4; ++nf) {
    float v = 0.f;
    #pragma unroll
    for (int mf = 0; mf < 4; ++mf)
      #pragma unroll
      for (int r = 0; r < 4; ++r) v += acc[mf][nf][r] * acc[mf][nf][r];
    v += __shfl_xor(v, 16, 64);
    v += __shfl_xor(v, 32, 64);
    if (l < 16) q[sOut * HN + n0 + ch * 64 + nf * 16 + l] = v;
  }
}

// ---------------------------------------------------------------------------
// finale: per sample combine T1, T2, sum g^2, pot+gint
__global__ __launch_bounds__(256) void k_fin(
    const float* __restrict__ wbuf, const float* __restrict__ a1,
    const float* __restrict__ dcoef, const float* __restrict__ q,
    const float* __restrict__ t1f, const float* __restrict__ W1T,
    const float* __restrict__ potgint, float* __restrict__ out) {
  __shared__ float s_lds[HN];
  __shared__ float gl[256];
  __shared__ float red1[4], red2[4];
  int s = blockIdx.x, tid = threadIdx.x;
  float p1 = 0.f, p2 = 0.f;
  #pragma unroll
  for (int cc = 0; cc < 4; ++cc) {
    int j = tid + cc * 256;
    float wv = wbuf[s * HN + j];
    p1 += a1[s * HN + j] * wv;
    p2 += dcoef[s * HN + j] * q[s * HN + j];
    s_lds[j] = t1f[s * HN + j] * wv;
  }
  __syncthreads();
  int part = tid >> 6, a = tid & 63;
  float gp = 0.f;
  for (int jj = part * 256; jj < part * 256 + 256; ++jj)
    gp += s_lds[jj] * W1T[jj * AN + a];
  gl[tid] = gp;
  #pragma unroll
  for (int o = 32; o > 0; o >>= 1) { p1 += __shfl_down(p1, o, 64); p2 += __shfl_down(p2, o, 64); }
  if ((tid & 63) == 0) { red1[tid >> 6] = p1; red2[tid >> 6] = p2; }
  __syncthreads();
  if (tid < 64) {
    float g = gl[tid] + gl[64 + tid] + gl[128 + tid] + gl[192 + tid];
    float sq = g * g;
    #pragma unroll
    for (int o = 32; o > 0; o >>= 1) sq += __shfl_down(sq, o, 64);
    if (tid == 0) {
      float T1 = -2.f * (red1[0] + red1[1] + red1[2] + red1[3]);
      float T2 = red2[0] + red2[1] + red2[2] + red2[3];
      out[s] = -0.5f * (T1 + T2 + sq) + potgint[s];
    }
  }
}

// ---------------------------------------------------------------------------
extern "C" void kernel_launch(void* const* d_in, const int* in_sizes, int n_in,
                              void* d_out, int out_size, void* d_ws, size_t ws_size,
                              hipStream_t stream) {
  const float* x  = (const float*)d_in[0];
  const float* W1 = (const float*)d_in[1];
  const float* b1 = (const float*)d_in[2];
  const float* W2 = (const float*)d_in[3];
  const float* b2 = (const float*)d_in[4];
  const float* W3 = (const float*)d_in[5];
  float* out = (float*)d_out;

  char* ws = (char*)d_ws;
  size_t off = 0;
  auto alloc = [&](size_t bytes) -> void* {
    void* p = ws + off; off += (bytes + 255) & ~(size_t)255; return p;
  };
  unsigned short* W2T  = (unsigned short*)alloc((size_t)HN * HN * 2);
  unsigned short* W2bf = (unsigned short*)alloc((size_t)HN * HN * 2);
  float*          W1T  = (float*)alloc((size_t)AN * HN * 4);
  float*          cj   = (float*)alloc((size_t)HN * 4);
  unsigned short* h1bf = (unsigned short*)alloc((size_t)BN * HN * 2);
  float*          t1f  = (float*)alloc((size_t)BN * HN * 4);
  float*          a1   = (float*)alloc((size_t)BN * HN * 4);
  float*          dcoef= (float*)alloc((size_t)BN * HN * 4);
  unsigned short* vbf  = (unsigned short*)alloc((size_t)BN * HN * 2);
  float*          wbuf = (float*)alloc((size_t)BN * HN * 4);
  float*          q    = (float*)alloc((size_t)BN * HN * 4);
  float*          pg   = (float*)alloc((size_t)BN * 4);

  k_prep<<<dim3(HN * HN / 256), 256, 0, stream>>>(W1, W2, W2T, W2bf, W1T, cj);
  k_fwd1<<<dim3(BN), 256, 0, stream>>>(x, W1, b1, cj, h1bf, t1f, a1, pg);
  k_z2<<<dim3(HN / 64, BN / 16), 256, 0, stream>>>(h1bf, W2T, b2, W3, dcoef, vbf);
  k_w<<<dim3(HN / 64, BN / 16), 256, 0, stream>>>(vbf, W2bf, wbuf);
  k_big<<<dim3(HN / 128, BN / 2), 256, 0, stream>>>(W1, t1f, W2T, q);
  k_fin<<<dim3(BN), 256, 0, stream>>>(wbuf, a1, dcoef, q, t1f, W1T, pg, out);
}